// Round 7
// baseline (360.963 us; speedup 1.0000x reference)
//
#include <hip/hip_runtime.h>

// SparseGCNConv: out = segment_sum(norm * f[src], dst, N) @ W^T + bias
// R12: R11 with the fusion bug fixed: bingemm's bin half ran at 256 threads
// but kept `if (t < NBKT)` (NBKT=391>256) for brank-zeroing and bbase
// reservation -> buckets 256..390 placed at garbage offsets (absmax 20).
// Both sites are now strided loops. Structure otherwise identical to R11:
//  D1 = hist ∥ cvtw, D2 = scan, D3 = bin ∥ gemm, D4 = sort(1024),
//  D5 = pull depth-3.

#define NN    100000
#define NE    3200000
#define D     128
#define NBKT  391    // ceil(NN/256); bucket b = dst >> 8
#define NI4   800000 // NE/4 int4 elements
#define NTILE 6250   // NN/16 node tiles (exact)
#define HB    782    // hist blocks (782*1024 int4 >= 800000)
#define BB    196    // bin blocks  (196*4096 int4 >= 800000)
#define GB    1563   // gemm blocks (1563*4 waves >= 6250 tiles)

typedef __attribute__((ext_vector_type(8))) short bf16x8;
typedef __attribute__((ext_vector_type(4))) float f32x4;

static __device__ __forceinline__ unsigned short f2bf(float x) {
  unsigned u = __float_as_uint(x);
  u += 0x7FFFu + ((u >> 16) & 1u);  // RTNE
  return (unsigned short)(u >> 16);
}

// 8 channels of one gathered f16 row-slice, scaled by nr, into f32 accs.
static __device__ __forceinline__ void fmix8(float* acc, uint4 q, float nr) {
  asm("v_fma_mix_f32 %0, %1, %2, %0 op_sel:[0,0,0] op_sel_hi:[1,0,0]"
      : "+v"(acc[0]) : "v"(q.x), "v"(nr));
  asm("v_fma_mix_f32 %0, %1, %2, %0 op_sel:[1,0,0] op_sel_hi:[1,0,0]"
      : "+v"(acc[1]) : "v"(q.x), "v"(nr));
  asm("v_fma_mix_f32 %0, %1, %2, %0 op_sel:[0,0,0] op_sel_hi:[1,0,0]"
      : "+v"(acc[2]) : "v"(q.y), "v"(nr));
  asm("v_fma_mix_f32 %0, %1, %2, %0 op_sel:[1,0,0] op_sel_hi:[1,0,0]"
      : "+v"(acc[3]) : "v"(q.y), "v"(nr));
  asm("v_fma_mix_f32 %0, %1, %2, %0 op_sel:[0,0,0] op_sel_hi:[1,0,0]"
      : "+v"(acc[4]) : "v"(q.z), "v"(nr));
  asm("v_fma_mix_f32 %0, %1, %2, %0 op_sel:[1,0,0] op_sel_hi:[1,0,0]"
      : "+v"(acc[5]) : "v"(q.z), "v"(nr));
  asm("v_fma_mix_f32 %0, %1, %2, %0 op_sel:[0,0,0] op_sel_hi:[1,0,0]"
      : "+v"(acc[6]) : "v"(q.w), "v"(nr));
  asm("v_fma_mix_f32 %0, %1, %2, %0 op_sel:[1,0,0] op_sel_hi:[1,0,0]"
      : "+v"(acc[7]) : "v"(q.w), "v"(nr));
}

// ---------------------------------------------------------------------------
// D1: blocks [0,HB) = bucket histogram; blocks [HB,HB+64) = W fp32->bf16
// fragment conversion (independent inputs, tiny).
__global__ __launch_bounds__(256) void histcvt_kernel(
    const int* __restrict__ dst, int* __restrict__ gcnt,
    const float* __restrict__ w, unsigned short* __restrict__ wfrag) {
  __shared__ int h[4][NBKT];
  const int t = threadIdx.x;
  if (blockIdx.x >= HB) {
    const int i = (blockIdx.x - HB) * 256 + t;  // 16384 elems, 64 blocks
    const int c = i >> 7, k = i & 127;
    const int pos = ((((c >> 4) << 2) + (k >> 5)) * 64 +
                     (((k >> 3) & 3) << 4) + (c & 15)) * 8 + (k & 7);
    wfrag[pos] = f2bf(w[i]);
    return;
  }
  for (int i = t; i < 4 * NBKT; i += 256) ((int*)h)[i] = 0;
  __syncthreads();
  const int i4base = blockIdx.x * 1024;
  const int rep = t & 3;
#pragma unroll
  for (int i = 0; i < 4; ++i) {
    const int idx = i4base + i * 256 + t;
    if (idx < NI4) {
      const int4 d = ((const int4*)dst)[idx];
      atomicAdd(&h[rep][d.x >> 8], 1);
      atomicAdd(&h[rep][d.y >> 8], 1);
      atomicAdd(&h[rep][d.z >> 8], 1);
      atomicAdd(&h[rep][d.w >> 8], 1);
    }
  }
  __syncthreads();
  for (int b = t; b < NBKT; b += 256) {
    const int v = h[0][b] + h[1][b] + h[2][b] + h[3][b];
    if (v) atomicAdd(&gcnt[b], v);
  }
}

// ---------------------------------------------------------------------------
// D2: exclusive scan of NBKT bucket counts -> bstart + cur_b.
__global__ __launch_bounds__(1024) void scan_kernel(const int* __restrict__ gcnt,
                                                    int* __restrict__ bstart,
                                                    int* __restrict__ cur_b,
                                                    int* __restrict__ row_ptr) {
  __shared__ int s[2048];
  const int t = threadIdx.x;
  s[t] = (t < NBKT) ? gcnt[t] : 0;
  s[t + 1024] = 0;
  __syncthreads();
  if (t < 64) {
    int part = 0;
#pragma unroll
    for (int i = 0; i < 32; ++i) part += s[(t << 5) + i];
    int inc = part;
#pragma unroll
    for (int off = 1; off < 64; off <<= 1) {
      int x = __shfl_up(inc, off, 64);
      if (t >= off) inc += x;
    }
    int run = inc - part;
#pragma unroll
    for (int i = 0; i < 32; ++i) {
      int idx = (t << 5) + i;
      int v = s[idx];
      s[idx] = run;
      run += v;
    }
  }
  __syncthreads();
  if (t < NBKT) { bstart[t] = s[t]; cur_b[t] = s[t]; }
  if (t == 0) { bstart[NBKT] = NE; row_ptr[NN] = NE; }
}

// ---------------------------------------------------------------------------
// D3: blocks [0,BB) = bin (4096 int4 = 16384 edges each, 16 int4/thread);
// blocks [BB,BB+GB) = MFMA gemm. bin first so its long blocks start at t=0
// and gemm hides under them. NOTE (R12): all per-bucket ops are strided
// loops -- blockDim (256) < NBKT (391).
__global__ __launch_bounds__(256) void bingemm_kernel(
    const int* __restrict__ src, const int* __restrict__ dst,
    const float* __restrict__ norm, int* __restrict__ cur_b,
    int2* __restrict__ bufA, const float* __restrict__ f,
    const unsigned short* __restrict__ wfrag, unsigned short* __restrict__ gh) {
  __shared__ int bcnt[4][NBKT];
  __shared__ int bbase[NBKT];
  __shared__ int brank[NBKT];
  const int t = threadIdx.x;
  if (blockIdx.x < BB) {
    for (int i = t; i < 4 * NBKT; i += 256) ((int*)bcnt)[i] = 0;
    for (int b = t; b < NBKT; b += 256) brank[b] = 0;  // R12 fix
    __syncthreads();
    const int i4base = blockIdx.x * 4096;
    const int rep = t & 3;
#pragma unroll 4
    for (int i = 0; i < 16; ++i) {
      const int idx = i4base + i * 256 + t;
      if (idx < NI4) {
        const int4 d = ((const int4*)dst)[idx];
        atomicAdd(&bcnt[rep][d.x >> 8], 1);
        atomicAdd(&bcnt[rep][d.y >> 8], 1);
        atomicAdd(&bcnt[rep][d.z >> 8], 1);
        atomicAdd(&bcnt[rep][d.w >> 8], 1);
      }
    }
    __syncthreads();
    for (int b = t; b < NBKT; b += 256) {  // R12 fix
      const int c = bcnt[0][b] + bcnt[1][b] + bcnt[2][b] + bcnt[3][b];
      if (c) bbase[b] = atomicAdd(&cur_b[b], c);
    }
    __syncthreads();
#pragma unroll 4
    for (int i = 0; i < 16; ++i) {
      const int idx = i4base + i * 256 + t;
      if (idx < NI4) {
        const int4 s = ((const int4*)src)[idx];
        const int4 d = ((const int4*)dst)[idx];
        const float4 nr = ((const float4*)norm)[idx];
        int bb, r; int2 m;
        bb = d.x >> 8; r = atomicAdd(&brank[bb], 1);
        m.x = s.x | ((d.x & 255) << 17); m.y = __float_as_int(nr.x);
        bufA[bbase[bb] + r] = m;
        bb = d.y >> 8; r = atomicAdd(&brank[bb], 1);
        m.x = s.y | ((d.y & 255) << 17); m.y = __float_as_int(nr.y);
        bufA[bbase[bb] + r] = m;
        bb = d.z >> 8; r = atomicAdd(&brank[bb], 1);
        m.x = s.z | ((d.z & 255) << 17); m.y = __float_as_int(nr.z);
        bufA[bbase[bb] + r] = m;
        bb = d.w >> 8; r = atomicAdd(&brank[bb], 1);
        m.x = s.w | ((d.w & 255) << 17); m.y = __float_as_int(nr.w);
        bufA[bbase[bb] + r] = m;
      }
    }
    return;
  }

  const int wv = (blockIdx.x - BB) * 4 + (t >> 6);
  if (wv >= NTILE) return;
  const int lane = t & 63;
  const int mrow = lane & 15;
  const int q = lane >> 4;
  const long node = (long)wv * 16 + mrow;
  const float* fr = f + node * D + q * 8;

  bf16x8 a[4];
#pragma unroll
  for (int ks = 0; ks < 4; ++ks) {
    const float4 lo = *(const float4*)(fr + ks * 32);
    const float4 hi = *(const float4*)(fr + ks * 32 + 4);
    union { bf16x8 v; unsigned short u[8]; } pa;
    pa.u[0] = f2bf(lo.x); pa.u[1] = f2bf(lo.y);
    pa.u[2] = f2bf(lo.z); pa.u[3] = f2bf(lo.w);
    pa.u[4] = f2bf(hi.x); pa.u[5] = f2bf(hi.y);
    pa.u[6] = f2bf(hi.z); pa.u[7] = f2bf(hi.w);
    a[ks] = pa.v;
  }

  const long nbase = (long)wv * 16 + (q << 2);
#pragma unroll
  for (int tc = 0; tc < 8; ++tc) {
    f32x4 acc = {0.f, 0.f, 0.f, 0.f};
#pragma unroll
    for (int ks = 0; ks < 4; ++ks) {
      const bf16x8 b =
          *(const bf16x8*)(wfrag + (((tc << 2) + ks) * 64 + lane) * 8);
      acc = __builtin_amdgcn_mfma_f32_16x16x32_bf16(a[ks], b, acc, 0, 0, 0);
    }
    const int c = (tc << 4) + mrow;
#pragma unroll
    for (int r = 0; r < 4; ++r) {
      union { _Float16 hh; unsigned short u; } cv;
      cv.hh = (_Float16)acc[r];  // v_cvt_f16_f32, RTNE
      gh[(nbase + r) * D + c] = cv.u;
    }
  }
}

// ---------------------------------------------------------------------------
// D4: per-bucket counting sort by local node (256 locals, 1024 thr/block).
__global__ __launch_bounds__(1024) void sort_kernel(
    const int2* __restrict__ bufA, const int* __restrict__ bstart,
    int2* __restrict__ bufB, int* __restrict__ row_ptr) {
  __shared__ int lcnt[256];
  __shared__ int lbase[256];
  __shared__ int wtot[4];
  const int b = blockIdx.x;
  const int t = threadIdx.x;
  const int beg = bstart[b];
  const int end = bstart[b + 1];
  if (t < 256) lcnt[t] = 0;
  __syncthreads();
  for (int e = beg + t; e < end; e += 1024)
    atomicAdd(&lcnt[(bufA[e].x >> 17) & 255], 1);
  __syncthreads();
  int v = 0, inc = 0;
  const int lane = t & 63;
  if (t < 256) {
    v = lcnt[t];
    inc = v;
#pragma unroll
    for (int off = 1; off < 64; off <<= 1) {
      int x = __shfl_up(inc, off, 64);
      if (lane >= off) inc += x;
    }
    if (lane == 63) wtot[t >> 6] = inc;
  }
  __syncthreads();
  if (t == 0) {
    int run = 0;
#pragma unroll
    for (int i = 0; i < 4; ++i) { int x = wtot[i]; wtot[i] = run; run += x; }
  }
  __syncthreads();
  if (t < 256) {
    const int ex = wtot[t >> 6] + inc - v;
    lbase[t] = ex;
    const int n = (b << 8) + t;
    if (n < NN) row_ptr[n] = beg + ex;
    lcnt[t] = 0;
  }
  __syncthreads();
  for (int e = beg + t; e < end; e += 1024) {
    const int2 m = bufA[e];
    const int nl = (m.x >> 17) & 255;
    const int r = atomicAdd(&lcnt[nl], 1);
    int2 o;
    o.x = m.x & 0x1FFFF;
    o.y = m.y;
    bufB[beg + lbase[nl] + r] = o;
  }
}

// ---------------------------------------------------------------------------
// D5: pull, depth-3 pipeline. One wave per node; 16 lanes per edge; dwordx4
// f16 gathers via fma_mix. In steady state: meta for blocks t+1..t+3 loaded,
// gathers for t and t+1 in flight (~8 outstanding VMEM/wave).
__global__ __launch_bounds__(256) void pull_kernel(
    const unsigned short* __restrict__ gh, const int* __restrict__ row_ptr,
    const int2* __restrict__ bufB, const float* __restrict__ bias,
    float* __restrict__ out) {
  const int n = blockIdx.x * 4 + (threadIdx.x >> 6);
  if (n >= NN) return;
  const int lane = threadIdx.x & 63;
  const int s = lane & 15;   // sublane: channels s*8 .. s*8+7
  const int g = lane >> 4;   // edge group
  const int beg = row_ptr[n];
  const int end = row_ptr[n + 1];

  float acc[8] = {0.f, 0.f, 0.f, 0.f, 0.f, 0.f, 0.f, 0.f};

  if (beg < end) {
    const char* gbase = (const char*)gh;
    const unsigned soff = (unsigned)(s << 4);  // byte offset within row
    const int last = end - 1;
    int e0 = beg;
    // meta blocks 0,1,2
    int2 mA0 = bufB[min(e0 + g, last)];
    int2 mB0 = bufB[min(e0 + 4 + g, last)];
    int2 mA1 = bufB[min(e0 + 8 + g, last)];
    int2 mB1 = bufB[min(e0 + 12 + g, last)];
    int2 mA2 = bufB[min(e0 + 16 + g, last)];
    int2 mB2 = bufB[min(e0 + 20 + g, last)];
    // gathers blocks 0,1
    uint4 qA0 = *(const uint4*)(gbase + (((unsigned)mA0.x << 8) + soff));
    uint4 qB0 = *(const uint4*)(gbase + (((unsigned)mB0.x << 8) + soff));
    uint4 qA1 = *(const uint4*)(gbase + (((unsigned)mA1.x << 8) + soff));
    uint4 qB1 = *(const uint4*)(gbase + (((unsigned)mB1.x << 8) + soff));
    while (e0 + 16 < end) {
      // issue block t+3 meta
      const int2 mA3 = bufB[min(e0 + 24 + g, last)];
      const int2 mB3 = bufB[min(e0 + 28 + g, last)];
      // issue block t+2 gathers (meta loaded 2 iterations ago)
      const uint4 qA2 =
          *(const uint4*)(gbase + (((unsigned)mA2.x << 8) + soff));
      const uint4 qB2 =
          *(const uint4*)(gbase + (((unsigned)mB2.x << 8) + soff));
      // consume block t (guaranteed full: end - e0 > 16)
      fmix8(acc, qA0, __int_as_float(mA0.y));
      fmix8(acc, qB0, __int_as_float(mB0.y));
      mA0 = mA1; mB0 = mB1;
      mA1 = mA2; mB1 = mB2;
      mA2 = mA3; mB2 = mB3;
      qA0 = qA1; qB0 = qB1;
      qA1 = qA2; qB1 = qB2;
      e0 += 8;
    }
    // epilogue: consume block t (maybe partial) and block t+1 (maybe empty),
    // both guarded via nr=0 on clamped lanes.
    {
      const float nrA = (e0 + g < end) ? __int_as_float(mA0.y) : 0.f;
      const float nrB = (e0 + 4 + g < end) ? __int_as_float(mB0.y) : 0.f;
      fmix8(acc, qA0, nrA);
      fmix8(acc, qB0, nrB);
    }
    {
      const float nrA = (e0 + 8 + g < end) ? __int_as_float(mA1.y) : 0.f;
      const float nrB = (e0 + 12 + g < end) ? __int_as_float(mB1.y) : 0.f;
      fmix8(acc, qA1, nrA);
      fmix8(acc, qB1, nrB);
    }
  }

#pragma unroll
  for (int k = 0; k < 8; ++k) {
    acc[k] += __shfl_xor(acc[k], 16, 64);
    acc[k] += __shfl_xor(acc[k], 32, 64);
  }
  if (g < 2) {
    const bool hi = (g == 1);
    const float r0 = hi ? acc[4] : acc[0];
    const float r1 = hi ? acc[5] : acc[1];
    const float r2 = hi ? acc[6] : acc[2];
    const float r3 = hi ? acc[7] : acc[3];
    const int cb = (s << 3) + (g << 2);
    const float4 b4 = *(const float4*)(bias + cb);
    float4 r;
    r.x = r0 + b4.x;
    r.y = r1 + b4.y;
    r.z = r2 + b4.z;
    r.w = r3 + b4.w;
    *(float4*)(out + (long)n * D + cb) = r;
  }
}

// ---------------------------------------------------------------------------
// Fallback (ws too small): R1 path.
__global__ __launch_bounds__(256) void gemm_f32_kernel(
    const float* __restrict__ f, const float* __restrict__ w,
    float* __restrict__ g) {
  __shared__ float wlds[D * D];
  const int t = threadIdx.x;
  for (int i = t; i < D * D; i += 256) {
    int c = i >> 7, k = i & 127;
    wlds[(c << 7) + (k ^ (c & 31))] = w[i];
  }
  __syncthreads();
  const int c = t & 127;
  const int cx = c & 31;
  const int cbase = c << 7;
  const int jbase = __builtin_amdgcn_readfirstlane((t >> 7) << 3);
  const long nb = (long)blockIdx.x * 16 + jbase;
  const float* __restrict__ frow = f + nb * D;
  float acc[8] = {0.f, 0.f, 0.f, 0.f, 0.f, 0.f, 0.f, 0.f};
#pragma unroll 4
  for (int k = 0; k < D; ++k) {
    float wv = wlds[cbase + (k ^ cx)];
#pragma unroll
    for (int j = 0; j < 8; ++j) acc[j] += frow[j * D + k] * wv;
  }
#pragma unroll
  for (int j = 0; j < 8; ++j) g[(nb + j) * D + c] = acc[j];
}

__global__ __launch_bounds__(256) void init_kernel(
    const float* __restrict__ bias, float4* __restrict__ out) {
  const int i = blockIdx.x * 256 + threadIdx.x;
  const float4* b4 = (const float4*)bias;
  out[i] = b4[i & 31];
}

__global__ __launch_bounds__(256) void scatter_kernel(
    const float* __restrict__ g, const float* __restrict__ norm,
    const int* __restrict__ src, const int* __restrict__ dst,
    float* __restrict__ out) {
  const long tid = (long)blockIdx.x * 256 + threadIdx.x;
  const int e = (int)(tid >> 5);
  if (e >= NE) return;
  const int ch = (int)(tid & 31) << 2;
  const int s = src[e];
  const int d = dst[e];
  const float nr = norm[e];
  const float4 gv = *(const float4*)(g + (long)s * D + ch);
  float* op = out + (long)d * D + ch;
  unsafeAtomicAdd(op + 0, nr * gv.x);
  unsafeAtomicAdd(op + 1, nr * gv.y);
  unsafeAtomicAdd(op + 2, nr * gv.z);
  unsafeAtomicAdd(op + 3, nr * gv.w);
}

// ---------------------------------------------------------------------------
extern "C" void kernel_launch(void* const* d_in, const int* in_sizes, int n_in,
                              void* d_out, int out_size, void* d_ws,
                              size_t ws_size, hipStream_t stream) {
  const float* features = (const float*)d_in[0];
  const float* norm     = (const float*)d_in[1];
  const int*   src      = (const int*)d_in[2];
  const int*   dst      = (const int*)d_in[3];
  const float* weight   = (const float*)d_in[4];
  const float* bias     = (const float*)d_in[5];
  float* out = (float*)d_out;

  char* ws = (char*)d_ws;
  unsigned short* gh    = (unsigned short*)ws;   // [0, 25.6M)  f16 g-matrix
  int2* bufA    = (int2*)(ws + 25600000);        // [25.6M, 51.2M)
  int2* bufB    = (int2*)(ws + 51200000);        // [51.2M, 76.8M)
  int*  row_ptr = (int*)(ws + 76800000);         // 400,004 B
  int*  gcnt    = (int*)(ws + 77200016);         // 1,564 B
  int*  bstart  = (int*)(ws + 77201584);         // 1,568 B
  int*  cur_b   = (int*)(ws + 77203152);         // 1,564 B
  unsigned short* wfrag = (unsigned short*)(ws + 77204720);  // 32,768 B
  const size_t need = 77237488;                  // ws >= 77,602,176 proven (R2)

  if (ws_size >= need) {
    hipMemsetAsync(gcnt, 0, NBKT * sizeof(int), stream);
    hipLaunchKernelGGL(histcvt_kernel, dim3(HB + 64), dim3(256), 0, stream,
                       dst, gcnt, weight, wfrag);
    hipLaunchKernelGGL(scan_kernel, dim3(1), dim3(1024), 0, stream,
                       gcnt, bstart, cur_b, row_ptr);
    hipLaunchKernelGGL(bingemm_kernel, dim3(BB + GB), dim3(256), 0, stream,
                       src, dst, norm, cur_b, bufA, features, wfrag, gh);
    hipLaunchKernelGGL(sort_kernel, dim3(NBKT), dim3(1024), 0, stream,
                       bufA, bstart, bufB, row_ptr);
    hipLaunchKernelGGL(pull_kernel, dim3((NN + 3) / 4), dim3(256), 0, stream,
                       gh, row_ptr, bufB, bias, out);
  } else {
    float* g = (float*)ws;
    hipLaunchKernelGGL(gemm_f32_kernel, dim3(NN / 16), dim3(256), 0, stream,
                       features, weight, g);
    hipLaunchKernelGGL(init_kernel, dim3((NN * D / 4) / 256), dim3(256), 0,
                       stream, bias, (float4*)out);
    hipLaunchKernelGGL(scatter_kernel, dim3((long)NE * 32 / 256), dim3(256), 0,
                       stream, g, norm, src, dst, out);
  }
}

// Round 8
// 343.896 us; speedup vs baseline: 1.0496x; 1.0496x over previous
//
#include <hip/hip_runtime.h>

// SparseGCNConv: out = segment_sum(norm * f[src], dst, N) @ W^T + bias
// R13: R10 structure (proven 340.6us) with the gemm moved from the hist
// launch into the SORT launch (sort was 391x512 = 0.76 blocks/CU, half the
// machine idle for ~65us; gemm's 782x512 blocks fill it). hist returns to
// the cvtw launch (R11's histcvt, verified correct). pull frozen at R8
// depth-2 (fabric-bound 105.7us; depth-3 A/B'd null in R12). bin is R10's
// proven 1024-thread standalone.
//  D1 = hist ∥ cvtw, D2 = scan, D3 = bin, D4 = sort ∥ gemm, D5 = pull.

#define NN    100000
#define NE    3200000
#define D     128
#define NBKT  391    // ceil(NN/256); bucket b = dst >> 8
#define NI4   800000 // NE/4 int4 elements
#define NTILE 6250   // NN/16 node tiles (exact)
#define HB    782    // hist blocks (782*1024 int4 >= 800000)
#define GB2   782    // gemm blocks in sortgemm (782*8 waves >= 6250 tiles)

typedef __attribute__((ext_vector_type(8))) short bf16x8;
typedef __attribute__((ext_vector_type(4))) float f32x4;

static __device__ __forceinline__ unsigned short f2bf(float x) {
  unsigned u = __float_as_uint(x);
  u += 0x7FFFu + ((u >> 16) & 1u);  // RTNE
  return (unsigned short)(u >> 16);
}

// 8 channels of one gathered f16 row-slice, scaled by nr, into f32 accs.
static __device__ __forceinline__ void fmix8(float* acc, uint4 q, float nr) {
  asm("v_fma_mix_f32 %0, %1, %2, %0 op_sel:[0,0,0] op_sel_hi:[1,0,0]"
      : "+v"(acc[0]) : "v"(q.x), "v"(nr));
  asm("v_fma_mix_f32 %0, %1, %2, %0 op_sel:[1,0,0] op_sel_hi:[1,0,0]"
      : "+v"(acc[1]) : "v"(q.x), "v"(nr));
  asm("v_fma_mix_f32 %0, %1, %2, %0 op_sel:[0,0,0] op_sel_hi:[1,0,0]"
      : "+v"(acc[2]) : "v"(q.y), "v"(nr));
  asm("v_fma_mix_f32 %0, %1, %2, %0 op_sel:[1,0,0] op_sel_hi:[1,0,0]"
      : "+v"(acc[3]) : "v"(q.y), "v"(nr));
  asm("v_fma_mix_f32 %0, %1, %2, %0 op_sel:[0,0,0] op_sel_hi:[1,0,0]"
      : "+v"(acc[4]) : "v"(q.z), "v"(nr));
  asm("v_fma_mix_f32 %0, %1, %2, %0 op_sel:[1,0,0] op_sel_hi:[1,0,0]"
      : "+v"(acc[5]) : "v"(q.z), "v"(nr));
  asm("v_fma_mix_f32 %0, %1, %2, %0 op_sel:[0,0,0] op_sel_hi:[1,0,0]"
      : "+v"(acc[6]) : "v"(q.w), "v"(nr));
  asm("v_fma_mix_f32 %0, %1, %2, %0 op_sel:[1,0,0] op_sel_hi:[1,0,0]"
      : "+v"(acc[7]) : "v"(q.w), "v"(nr));
}

// ---------------------------------------------------------------------------
// D1: blocks [0,HB) = bucket histogram; blocks [HB,HB+64) = W fp32->bf16
// fragment conversion (independent inputs). Verified correct in R11/R12.
__global__ __launch_bounds__(256) void histcvt_kernel(
    const int* __restrict__ dst, int* __restrict__ gcnt,
    const float* __restrict__ w, unsigned short* __restrict__ wfrag) {
  __shared__ int h[4][NBKT];
  const int t = threadIdx.x;
  if (blockIdx.x >= HB) {
    const int i = (blockIdx.x - HB) * 256 + t;  // 16384 elems, 64 blocks
    const int c = i >> 7, k = i & 127;
    const int pos = ((((c >> 4) << 2) + (k >> 5)) * 64 +
                     (((k >> 3) & 3) << 4) + (c & 15)) * 8 + (k & 7);
    wfrag[pos] = f2bf(w[i]);
    return;
  }
  for (int i = t; i < 4 * NBKT; i += 256) ((int*)h)[i] = 0;
  __syncthreads();
  const int i4base = blockIdx.x * 1024;
  const int rep = t & 3;
#pragma unroll
  for (int i = 0; i < 4; ++i) {
    const int idx = i4base + i * 256 + t;
    if (idx < NI4) {
      const int4 d = ((const int4*)dst)[idx];
      atomicAdd(&h[rep][d.x >> 8], 1);
      atomicAdd(&h[rep][d.y >> 8], 1);
      atomicAdd(&h[rep][d.z >> 8], 1);
      atomicAdd(&h[rep][d.w >> 8], 1);
    }
  }
  __syncthreads();
  for (int b = t; b < NBKT; b += 256) {
    const int v = h[0][b] + h[1][b] + h[2][b] + h[3][b];
    if (v) atomicAdd(&gcnt[b], v);
  }
}

// ---------------------------------------------------------------------------
// D2: exclusive scan of NBKT bucket counts -> bstart + cur_b.  (proven)
__global__ __launch_bounds__(1024) void scan_kernel(const int* __restrict__ gcnt,
                                                    int* __restrict__ bstart,
                                                    int* __restrict__ cur_b,
                                                    int* __restrict__ row_ptr) {
  __shared__ int s[2048];
  const int t = threadIdx.x;
  s[t] = (t < NBKT) ? gcnt[t] : 0;
  s[t + 1024] = 0;
  __syncthreads();
  if (t < 64) {
    int part = 0;
#pragma unroll
    for (int i = 0; i < 32; ++i) part += s[(t << 5) + i];
    int inc = part;
#pragma unroll
    for (int off = 1; off < 64; off <<= 1) {
      int x = __shfl_up(inc, off, 64);
      if (t >= off) inc += x;
    }
    int run = inc - part;
#pragma unroll
    for (int i = 0; i < 32; ++i) {
      int idx = (t << 5) + i;
      int v = s[idx];
      s[idx] = run;
      run += v;
    }
  }
  __syncthreads();
  if (t < NBKT) { bstart[t] = s[t]; cur_b[t] = s[t]; }
  if (t == 0) { bstart[NBKT] = NE; row_ptr[NN] = NE; }
}

// ---------------------------------------------------------------------------
// D3: bin edges into 256-node buckets (R10's proven 1024-thread version).
// Pack: m.x = src | ((dst & 255) << 17)  (src < 2^17).
__global__ __launch_bounds__(1024) void bin_kernel(
    const int* __restrict__ src, const int* __restrict__ dst,
    const float* __restrict__ norm, int* __restrict__ cur_b,
    int2* __restrict__ bufA) {
  __shared__ int bcnt[4][NBKT];
  __shared__ int bbase[NBKT];
  __shared__ int brank[NBKT];
  const int t = threadIdx.x;
  for (int i = t; i < 4 * NBKT; i += 1024) ((int*)bcnt)[i] = 0;
  if (t < NBKT) brank[t] = 0;
  __syncthreads();
  const int i4base = blockIdx.x * 4096;
  const int rep = t & 3;
#pragma unroll
  for (int i = 0; i < 4; ++i) {
    const int idx = i4base + i * 1024 + t;
    if (idx < NI4) {
      const int4 d = ((const int4*)dst)[idx];
      atomicAdd(&bcnt[rep][d.x >> 8], 1);
      atomicAdd(&bcnt[rep][d.y >> 8], 1);
      atomicAdd(&bcnt[rep][d.z >> 8], 1);
      atomicAdd(&bcnt[rep][d.w >> 8], 1);
    }
  }
  __syncthreads();
  if (t < NBKT) {
    const int c = bcnt[0][t] + bcnt[1][t] + bcnt[2][t] + bcnt[3][t];
    if (c) bbase[t] = atomicAdd(&cur_b[t], c);
  }
  __syncthreads();
#pragma unroll
  for (int i = 0; i < 4; ++i) {
    const int idx = i4base + i * 1024 + t;
    if (idx < NI4) {
      const int4 s = ((const int4*)src)[idx];
      const int4 d = ((const int4*)dst)[idx];
      const float4 nr = ((const float4*)norm)[idx];
      int bb, r; int2 m;
      bb = d.x >> 8; r = atomicAdd(&brank[bb], 1);
      m.x = s.x | ((d.x & 255) << 17); m.y = __float_as_int(nr.x);
      bufA[bbase[bb] + r] = m;
      bb = d.y >> 8; r = atomicAdd(&brank[bb], 1);
      m.x = s.y | ((d.y & 255) << 17); m.y = __float_as_int(nr.y);
      bufA[bbase[bb] + r] = m;
      bb = d.z >> 8; r = atomicAdd(&brank[bb], 1);
      m.x = s.z | ((d.z & 255) << 17); m.y = __float_as_int(nr.z);
      bufA[bbase[bb] + r] = m;
      bb = d.w >> 8; r = atomicAdd(&brank[bb], 1);
      m.x = s.w | ((d.w & 255) << 17); m.y = __float_as_int(nr.w);
      bufA[bbase[bb] + r] = m;
    }
  }
}

// ---------------------------------------------------------------------------
// D4: blocks [0,NBKT) = per-bucket counting sort (R10's proven 512-thread
// body); blocks [NBKT,NBKT+GB2) = MFMA gemm (8 waves/block). Sort blocks
// first so they start at t=0; gemm fills the otherwise-idle CUs.
__global__ __launch_bounds__(512) void sortgemm_kernel(
    const int2* __restrict__ bufA, const int* __restrict__ bstart,
    int2* __restrict__ bufB, int* __restrict__ row_ptr,
    const float* __restrict__ f, const unsigned short* __restrict__ wfrag,
    unsigned short* __restrict__ gh) {
  __shared__ int lcnt[256];
  __shared__ int lbase[256];
  __shared__ int wtot[4];
  const int t = threadIdx.x;
  if (blockIdx.x < NBKT) {
    const int b = blockIdx.x;
    const int beg = bstart[b];
    const int end = bstart[b + 1];
    if (t < 256) lcnt[t] = 0;
    __syncthreads();
    for (int e = beg + t; e < end; e += 512)
      atomicAdd(&lcnt[(bufA[e].x >> 17) & 255], 1);
    __syncthreads();
    int v = 0, inc = 0;
    const int lane = t & 63;
    if (t < 256) {
      v = lcnt[t];
      inc = v;
#pragma unroll
      for (int off = 1; off < 64; off <<= 1) {
        int x = __shfl_up(inc, off, 64);
        if (lane >= off) inc += x;
      }
      if (lane == 63) wtot[t >> 6] = inc;
    }
    __syncthreads();
    if (t == 0) {
      int run = 0;
#pragma unroll
      for (int i = 0; i < 4; ++i) { int x = wtot[i]; wtot[i] = run; run += x; }
    }
    __syncthreads();
    if (t < 256) {
      const int ex = wtot[t >> 6] + inc - v;
      lbase[t] = ex;
      const int n = (b << 8) + t;
      if (n < NN) row_ptr[n] = beg + ex;
      lcnt[t] = 0;
    }
    __syncthreads();
    for (int e = beg + t; e < end; e += 512) {
      const int2 m = bufA[e];
      const int nl = (m.x >> 17) & 255;
      const int r = atomicAdd(&lcnt[nl], 1);
      int2 o;
      o.x = m.x & 0x1FFFF;
      o.y = m.y;
      bufB[beg + lbase[nl] + r] = o;
    }
    return;
  }

  const int wv = (blockIdx.x - NBKT) * 8 + (t >> 6);
  if (wv >= NTILE) return;
  const int lane = t & 63;
  const int mrow = lane & 15;
  const int q = lane >> 4;
  const long node = (long)wv * 16 + mrow;
  const float* fr = f + node * D + q * 8;

  bf16x8 a[4];
#pragma unroll
  for (int ks = 0; ks < 4; ++ks) {
    const float4 lo = *(const float4*)(fr + ks * 32);
    const float4 hi = *(const float4*)(fr + ks * 32 + 4);
    union { bf16x8 v; unsigned short u[8]; } pa;
    pa.u[0] = f2bf(lo.x); pa.u[1] = f2bf(lo.y);
    pa.u[2] = f2bf(lo.z); pa.u[3] = f2bf(lo.w);
    pa.u[4] = f2bf(hi.x); pa.u[5] = f2bf(hi.y);
    pa.u[6] = f2bf(hi.z); pa.u[7] = f2bf(hi.w);
    a[ks] = pa.v;
  }

  const long nbase = (long)wv * 16 + (q << 2);
#pragma unroll
  for (int tc = 0; tc < 8; ++tc) {
    f32x4 acc = {0.f, 0.f, 0.f, 0.f};
#pragma unroll
    for (int ks = 0; ks < 4; ++ks) {
      const bf16x8 b =
          *(const bf16x8*)(wfrag + (((tc << 2) + ks) * 64 + lane) * 8);
      acc = __builtin_amdgcn_mfma_f32_16x16x32_bf16(a[ks], b, acc, 0, 0, 0);
    }
    const int c = (tc << 4) + mrow;
#pragma unroll
    for (int r = 0; r < 4; ++r) {
      union { _Float16 hh; unsigned short u; } cv;
      cv.hh = (_Float16)acc[r];  // v_cvt_f16_f32, RTNE
      gh[(nbase + r) * D + c] = cv.u;
    }
  }
}

// ---------------------------------------------------------------------------
// D5: pull — FROZEN at R8 depth-2 (fabric-bound 105.7us; depth-3 null).
// One wave per node; 16 lanes per edge; dwordx4 f16 gathers via fma_mix.
__global__ __launch_bounds__(256) void pull_kernel(
    const unsigned short* __restrict__ gh, const int* __restrict__ row_ptr,
    const int2* __restrict__ bufB, const float* __restrict__ bias,
    float* __restrict__ out) {
  const int n = blockIdx.x * 4 + (threadIdx.x >> 6);
  if (n >= NN) return;
  const int lane = threadIdx.x & 63;
  const int s = lane & 15;   // sublane: channels s*8 .. s*8+7
  const int g = lane >> 4;   // edge group
  const int beg = row_ptr[n];
  const int end = row_ptr[n + 1];

  float acc[8] = {0.f, 0.f, 0.f, 0.f, 0.f, 0.f, 0.f, 0.f};

  if (beg < end) {
    const char* gbase = (const char*)gh;
    const unsigned soff = (unsigned)(s << 4);  // byte offset within row
    const int last = end - 1;
    int e0 = beg;
    int2 mA0 = bufB[min(e0 + g, last)];
    int2 mB0 = bufB[min(e0 + 4 + g, last)];
    uint4 qA0 = *(const uint4*)(gbase + (((unsigned)mA0.x << 8) + soff));
    uint4 qB0 = *(const uint4*)(gbase + (((unsigned)mB0.x << 8) + soff));
    int2 mA1 = bufB[min(e0 + 8 + g, last)];
    int2 mB1 = bufB[min(e0 + 12 + g, last)];
    while (e0 + 8 < end) {
      const int2 mA2 = bufB[min(e0 + 16 + g, last)];
      const int2 mB2 = bufB[min(e0 + 20 + g, last)];
      const uint4 qA1 =
          *(const uint4*)(gbase + (((unsigned)mA1.x << 8) + soff));
      const uint4 qB1 =
          *(const uint4*)(gbase + (((unsigned)mB1.x << 8) + soff));
      fmix8(acc, qA0, __int_as_float(mA0.y));
      fmix8(acc, qB0, __int_as_float(mB0.y));
      mA0 = mA1; mB0 = mB1;
      mA1 = mA2; mB1 = mB2;
      qA0 = qA1; qB0 = qB1;
      e0 += 8;
    }
    const float nrA = (e0 + g < end) ? __int_as_float(mA0.y) : 0.f;
    const float nrB = (e0 + 4 + g < end) ? __int_as_float(mB0.y) : 0.f;
    fmix8(acc, qA0, nrA);
    fmix8(acc, qB0, nrB);
  }

#pragma unroll
  for (int k = 0; k < 8; ++k) {
    acc[k] += __shfl_xor(acc[k], 16, 64);
    acc[k] += __shfl_xor(acc[k], 32, 64);
  }
  if (g < 2) {
    const bool hi = (g == 1);
    const float r0 = hi ? acc[4] : acc[0];
    const float r1 = hi ? acc[5] : acc[1];
    const float r2 = hi ? acc[6] : acc[2];
    const float r3 = hi ? acc[7] : acc[3];
    const int cb = (s << 3) + (g << 2);
    const float4 b4 = *(const float4*)(bias + cb);
    float4 r;
    r.x = r0 + b4.x;
    r.y = r1 + b4.y;
    r.z = r2 + b4.z;
    r.w = r3 + b4.w;
    *(float4*)(out + (long)n * D + cb) = r;
  }
}

// ---------------------------------------------------------------------------
// Fallback (ws too small): R1 path.
__global__ __launch_bounds__(256) void gemm_f32_kernel(
    const float* __restrict__ f, const float* __restrict__ w,
    float* __restrict__ g) {
  __shared__ float wlds[D * D];
  const int t = threadIdx.x;
  for (int i = t; i < D * D; i += 256) {
    int c = i >> 7, k = i & 127;
    wlds[(c << 7) + (k ^ (c & 31))] = w[i];
  }
  __syncthreads();
  const int c = t & 127;
  const int cx = c & 31;
  const int cbase = c << 7;
  const int jbase = __builtin_amdgcn_readfirstlane((t >> 7) << 3);
  const long nb = (long)blockIdx.x * 16 + jbase;
  const float* __restrict__ frow = f + nb * D;
  float acc[8] = {0.f, 0.f, 0.f, 0.f, 0.f, 0.f, 0.f, 0.f};
#pragma unroll 4
  for (int k = 0; k < D; ++k) {
    float wv = wlds[cbase + (k ^ cx)];
#pragma unroll
    for (int j = 0; j < 8; ++j) acc[j] += frow[j * D + k] * wv;
  }
#pragma unroll
  for (int j = 0; j < 8; ++j) g[(nb + j) * D + c] = acc[j];
}

__global__ __launch_bounds__(256) void init_kernel(
    const float* __restrict__ bias, float4* __restrict__ out) {
  const int i = blockIdx.x * 256 + threadIdx.x;
  const float4* b4 = (const float4*)bias;
  out[i] = b4[i & 31];
}

__global__ __launch_bounds__(256) void scatter_kernel(
    const float* __restrict__ g, const float* __restrict__ norm,
    const int* __restrict__ src, const int* __restrict__ dst,
    float* __restrict__ out) {
  const long tid = (long)blockIdx.x * 256 + threadIdx.x;
  const int e = (int)(tid >> 5);
  if (e >= NE) return;
  const int ch = (int)(tid & 31) << 2;
  const int s = src[e];
  const int d = dst[e];
  const float nr = norm[e];
  const float4 gv = *(const float4*)(g + (long)s * D + ch);
  float* op = out + (long)d * D + ch;
  unsafeAtomicAdd(op + 0, nr * gv.x);
  unsafeAtomicAdd(op + 1, nr * gv.y);
  unsafeAtomicAdd(op + 2, nr * gv.z);
  unsafeAtomicAdd(op + 3, nr * gv.w);
}

// ---------------------------------------------------------------------------
extern "C" void kernel_launch(void* const* d_in, const int* in_sizes, int n_in,
                              void* d_out, int out_size, void* d_ws,
                              size_t ws_size, hipStream_t stream) {
  const float* features = (const float*)d_in[0];
  const float* norm     = (const float*)d_in[1];
  const int*   src      = (const int*)d_in[2];
  const int*   dst      = (const int*)d_in[3];
  const float* weight   = (const float*)d_in[4];
  const float* bias     = (const float*)d_in[5];
  float* out = (float*)d_out;

  char* ws = (char*)d_ws;
  unsigned short* gh    = (unsigned short*)ws;   // [0, 25.6M)  f16 g-matrix
  int2* bufA    = (int2*)(ws + 25600000);        // [25.6M, 51.2M)
  int2* bufB    = (int2*)(ws + 51200000);        // [51.2M, 76.8M)
  int*  row_ptr = (int*)(ws + 76800000);         // 400,004 B
  int*  gcnt    = (int*)(ws + 77200016);         // 1,564 B
  int*  bstart  = (int*)(ws + 77201584);         // 1,568 B
  int*  cur_b   = (int*)(ws + 77203152);         // 1,564 B
  unsigned short* wfrag = (unsigned short*)(ws + 77204720);  // 32,768 B
  const size_t need = 77237488;                  // ws >= 77,602,176 proven (R2)

  if (ws_size >= need) {
    hipMemsetAsync(gcnt, 0, NBKT * sizeof(int), stream);
    hipLaunchKernelGGL(histcvt_kernel, dim3(HB + 64), dim3(256), 0, stream,
                       dst, gcnt, weight, wfrag);
    hipLaunchKernelGGL(scan_kernel, dim3(1), dim3(1024), 0, stream,
                       gcnt, bstart, cur_b, row_ptr);
    hipLaunchKernelGGL(bin_kernel, dim3((NI4 + 4095) / 4096), dim3(1024), 0,
                       stream, src, dst, norm, cur_b, bufA);
    hipLaunchKernelGGL(sortgemm_kernel, dim3(NBKT + GB2), dim3(512), 0, stream,
                       bufA, bstart, bufB, row_ptr, features, wfrag, gh);
    hipLaunchKernelGGL(pull_kernel, dim3((NN + 3) / 4), dim3(256), 0, stream,
                       gh, row_ptr, bufB, bias, out);
  } else {
    float* g = (float*)ws;
    hipLaunchKernelGGL(gemm_f32_kernel, dim3(NN / 16), dim3(256), 0, stream,
                       features, weight, g);
    hipLaunchKernelGGL(init_kernel, dim3((NN * D / 4) / 256), dim3(256), 0,
                       stream, bias, (float4*)out);
    hipLaunchKernelGGL(scatter_kernel, dim3((long)NE * 32 / 256), dim3(256), 0,
                       stream, g, norm, src, dst, out);
  }
}